// Round 3
// baseline (294.623 us; speedup 1.0000x reference)
//
#include <hip/hip_runtime.h>

typedef _Float16 f16;
typedef __attribute__((ext_vector_type(8))) _Float16 f16x8;
typedef __attribute__((ext_vector_type(4))) float    f32x4;

#define NP 13          // Wn0..6 -> p=0..6, Ws0..5 -> p=7..12; result = outputs[7]
#define THREADS 512    // 8 waves/block, 1 block/CU (LDS ~105 KB)
#define NBLOCKS 256

// Verified-by-R2 conventions for mfma_f32_16x16x32_f16 (D[m][n] = sum_k A[m][k]B[n][k]):
//   A frag: lane(q=lane>>4, l15=lane&15) holds A[m=l15][k=q*8+j], j=0..7
//   B frag: lane holds B[n=l15][k=q*8+j]   (identical map)
//   C/D:    col(n)=l15, row(m)=q*4+reg
// Orientation-2: A = W (m=feature_out), B = h (n=batch). C then has batch on lanes,
// so C -> next-layer B-frag needs NO cross-lane movement.
// k-slot permutation (consistent across all operands, cancels in the MFMA sum):
//   slot (q, kb, jh, jl)  <->  feature F = kb*32 + jh*16 + q*4 + jl
// so a lane's C regs (features ft*16+q*4+r at reg r) pack directly into B-frags.
// Weights are stored column-permuted (F -> slot) + XOR-swizzled 16B chunks in LDS.
__global__ __launch_bounds__(THREADS, 2)
void nn_fused(const float* __restrict__ x,
              const float* __restrict__ Wn, const float* __restrict__ bn,
              const float* __restrict__ Ws, const float* __restrict__ bs,
              float* __restrict__ out)
{
    __shared__ f16 w_lds[NP * 4096];   // [p][f=64][slot=64], 16B chunks XOR-swizzled by f&7
    __shared__ f16 b_lds[NP * 64];     // [p][f] f16 biases

    const int tid = threadIdx.x;

    // ---- stage weights: dest chunk ch=(q<<1|kb) holds slots with jh=0..1, jl=0..3 ----
    for (int c = tid; c < NP * 512; c += THREADS) {
        const int p = c >> 9, f = (c >> 3) & 63, ch = c & 7;
        const int qq = ch >> 1, kb = ch & 1;
        const float* src = (p < 7 ? Wn + p * 4096 : Ws + (p - 7) * 4096) + f * 64;
        f32x4 a, b;
        __builtin_memcpy(&a, src + kb * 32 + qq * 4, 16);       // jh=0: features kb*32+q*4+jl
        __builtin_memcpy(&b, src + kb * 32 + 16 + qq * 4, 16);  // jh=1: +16
        f16x8 v;
        v[0]=(f16)a.x; v[1]=(f16)a.y; v[2]=(f16)a.z; v[3]=(f16)a.w;
        v[4]=(f16)b.x; v[5]=(f16)b.y; v[6]=(f16)b.z; v[7]=(f16)b.w;
        __builtin_memcpy(&w_lds[p * 4096 + f * 64 + ((ch ^ (f & 7)) << 3)], &v, 16);
    }
    for (int i = tid; i < NP * 64; i += THREADS) {
        const int p = i >> 6, f = i & 63;
        b_lds[i] = (f16)((p < 7) ? bn[p * 64 + f] : bs[(p - 7) * 64 + f]);
    }
    __syncthreads();   // only barrier in the kernel

    const int lane = tid & 63;
    const int wid  = tid >> 6;
    const int l15  = lane & 15;
    const int q    = lane >> 4;
    const int gw   = blockIdx.x * (THREADS / 64) + wid;   // 0..2047

    auto wfrag = [&](int p, int ft, int kb) -> f16x8 {     // A-operand: W rows
        const int f = ft * 16 + l15;
        const int chs = ((q << 1) | kb) ^ (f & 7);
        f16x8 v;
        __builtin_memcpy(&v, &w_lds[p * 4096 + f * 64 + (chs << 3)], 16);
        return v;
    };
    struct BiasPk { f16 h[4]; };
    auto biaspk = [&](int p, int ft) -> BiasPk {           // lane's 4 biases f=ft*16+q*4+r
        BiasPk b;
        __builtin_memcpy(&b, &b_lds[p * 64 + ft * 16 + q * 4], 8);
        return b;
    };

    for (int g = 0; g < 2; ++g) {
        // two tiles of 32 rows: tile = gw*2+tt + g*4096
        f16x8 hp[2][2][2], hp2[2][2][2];   // [tt][nb][kb]  (h_{l-1}, h_{l-2} B-frags)

        // ---- x -> B-frags in permuted slot order ----
#pragma unroll
        for (int tt = 0; tt < 2; ++tt)
#pragma unroll
        for (int nb = 0; nb < 2; ++nb) {
            const long row = ((long)(gw * 2 + tt) + (long)g * 4096) * 32 + nb * 16 + l15;
            const float* xr = x + row * 64;
#pragma unroll
            for (int kb = 0; kb < 2; ++kb) {
                f32x4 a, b;
                __builtin_memcpy(&a, xr + kb * 32 + q * 4, 16);
                __builtin_memcpy(&b, xr + kb * 32 + 16 + q * 4, 16);
                f16x8 v;
                v[0]=(f16)a.x; v[1]=(f16)a.y; v[2]=(f16)a.z; v[3]=(f16)a.w;
                v[4]=(f16)b.x; v[5]=(f16)b.y; v[6]=(f16)b.z; v[7]=(f16)b.w;
                hp[tt][nb][kb] = v;
            }
        }

        // ---- layers 1..7, layer-outer so W-frags are loaded once per layer ----
#pragma unroll
        for (int l = 1; l <= 7; ++l) {
            const int pn = l - 1;
            const int ps = (l >= 2) ? (5 + l) : -1;     // 7 + (l-2)

            f16x8 wnf[4][2], wsf[4][2];
            BiasPk bnp[4], bsp[4];
#pragma unroll
            for (int ft = 0; ft < 4; ++ft) {
                bnp[ft] = biaspk(pn, ft);
                if (ps >= 0) bsp[ft] = biaspk(ps, ft);
#pragma unroll
                for (int kb = 0; kb < 2; ++kb) {
                    wnf[ft][kb] = wfrag(pn, ft, kb);
                    if (ps >= 0) wsf[ft][kb] = wfrag(ps, ft, kb);
                }
            }

            f16x8 hnew[2][2][2];
#pragma unroll
            for (int tt = 0; tt < 2; ++tt)
#pragma unroll
            for (int nb = 0; nb < 2; ++nb) {
                float vres[4][4];   // [ft][r] : feature ft*16+q*4+r, batch nb*16+l15
#pragma unroll
                for (int ft = 0; ft < 4; ++ft) {
                    f32x4 accn = {0.f, 0.f, 0.f, 0.f};
                    accn = __builtin_amdgcn_mfma_f32_16x16x32_f16(wnf[ft][0], hp[tt][nb][0], accn, 0, 0, 0);
                    accn = __builtin_amdgcn_mfma_f32_16x16x32_f16(wnf[ft][1], hp[tt][nb][1], accn, 0, 0, 0);
                    if (ps >= 0) {
                        f32x4 accs = {0.f, 0.f, 0.f, 0.f};
                        accs = __builtin_amdgcn_mfma_f32_16x16x32_f16(wsf[ft][0], hp2[tt][nb][0], accs, 0, 0, 0);
                        accs = __builtin_amdgcn_mfma_f32_16x16x32_f16(wsf[ft][1], hp2[tt][nb][1], accs, 0, 0, 0);
#pragma unroll
                        for (int r = 0; r < 4; ++r)
                            vres[ft][r] = fmaxf(accn[r] + (float)bnp[ft].h[r], 0.f)
                                        + fmaxf(accs[r] + (float)bsp[ft].h[r], 0.f);
                    } else {
#pragma unroll
                        for (int r = 0; r < 4; ++r)
                            vres[ft][r] = fmaxf(accn[r] + (float)bnp[ft].h[r], 0.f);
                    }
                }
                if (l == 7) {
                    const long row = ((long)(gw * 2 + tt) + (long)g * 4096) * 32 + nb * 16 + l15;
                    float* orow = out + row * 64;
#pragma unroll
                    for (int ft = 0; ft < 4; ++ft) {
                        f32x4 v = {vres[ft][0], vres[ft][1], vres[ft][2], vres[ft][3]};
                        __builtin_memcpy(orow + ft * 16 + q * 4, &v, 16);
                    }
                } else {
                    // pack to next-layer B-frags: slot (q,kb,jh,jl) = feature kb*32+jh*16+q*4+jl
#pragma unroll
                    for (int kb = 0; kb < 2; ++kb) {
                        f16x8 v;
#pragma unroll
                        for (int jh = 0; jh < 2; ++jh)
#pragma unroll
                        for (int jl = 0; jl < 4; ++jl)
                            v[jh * 4 + jl] = (f16)vres[kb * 2 + jh][jl];
                        hnew[tt][nb][kb] = v;
                    }
                }
            }
            if (l < 7) {
#pragma unroll
                for (int tt = 0; tt < 2; ++tt)
#pragma unroll
                for (int nb = 0; nb < 2; ++nb)
#pragma unroll
                for (int kb = 0; kb < 2; ++kb) {
                    hp2[tt][nb][kb] = hp[tt][nb][kb];
                    hp[tt][nb][kb]  = hnew[tt][nb][kb];
                }
            }
        }
    }
}

extern "C" void kernel_launch(void* const* d_in, const int* in_sizes, int n_in,
                              void* d_out, int out_size, void* d_ws, size_t ws_size,
                              hipStream_t stream) {
    (void)in_sizes; (void)n_in; (void)d_ws; (void)ws_size; (void)out_size;
    const float* x  = (const float*)d_in[0];
    const float* Wn = (const float*)d_in[1];
    const float* bn = (const float*)d_in[2];
    const float* Ws = (const float*)d_in[3];
    const float* bs = (const float*)d_in[4];
    nn_fused<<<dim3(NBLOCKS), dim3(THREADS), 0, stream>>>(x, Wn, bn, Ws, bs, (float*)d_out);
}

// Round 4
// 163.157 us; speedup vs baseline: 1.8058x; 1.8058x over previous
//
#include <hip/hip_runtime.h>

typedef _Float16 f16;
typedef __attribute__((ext_vector_type(8))) _Float16 f16x8;
typedef __attribute__((ext_vector_type(4))) float    f32x4;

#define NP 13          // Wn0..6 -> p=0..6, Ws0..5 -> p=7..12; result = outputs[7]
#define THREADS 512    // 8 waves/block, 1 block/CU (LDS ~105 KB) -> 8 waves/CU
#define NBLOCKS 256
#define TILES 2        // 2048 waves * 2 tiles * 64 rows = 262144

// Verified (R2/R3 passes) conventions for mfma_f32_16x16x32_f16, D[m][n]=sum_k A[m][k]B[n][k]:
//   A/B frag: lane(q=lane>>4, l15=lane&15) holds [m|n = l15][k = q*8+j], j=0..7
//   C/D:      col(n)=l15, row(m)=q*4+reg
// A = W (m = output feature), B = h (n = batch row). C has batch on lanes -> C feeds the
// next layer's B-frag with NO cross-lane movement, using the k-slot permutation
//   slot(q,kb,jh,jl) <-> feature F = kb*32 + jh*16 + q*4 + jl
// baked into the LDS weight layout (k is a dummy index; permutation cancels in the sum).
__global__ __launch_bounds__(THREADS)   // NO min-occupancy arg: R3 showed it caps VGPR at 128
void nn_fused(const float* __restrict__ x,
              const float* __restrict__ Wn, const float* __restrict__ bn,
              const float* __restrict__ Ws, const float* __restrict__ bs,
              float* __restrict__ out)
{
    __shared__ f16 w_lds[NP * 4096];   // [p][f=64][slot=64], 16B chunks XOR-swizzled by f&7
    __shared__ f16 b_lds[NP * 64];

    const int tid = threadIdx.x;

    // ---- stage weights: dest chunk ch=(q<<1|kb) holds slots with jh=0..1, jl=0..3 ----
    for (int c = tid; c < NP * 512; c += THREADS) {
        const int p = c >> 9, f = (c >> 3) & 63, ch = c & 7;
        const int qq = ch >> 1, kb = ch & 1;
        const float* src = (p < 7 ? Wn + p * 4096 : Ws + (p - 7) * 4096) + f * 64;
        f32x4 a, b;
        __builtin_memcpy(&a, src + kb * 32 + qq * 4, 16);       // jh=0: features kb*32+qq*4+jl
        __builtin_memcpy(&b, src + kb * 32 + 16 + qq * 4, 16);  // jh=1: +16
        f16x8 v;
        v[0]=(f16)a.x; v[1]=(f16)a.y; v[2]=(f16)a.z; v[3]=(f16)a.w;
        v[4]=(f16)b.x; v[5]=(f16)b.y; v[6]=(f16)b.z; v[7]=(f16)b.w;
        __builtin_memcpy(&w_lds[p * 4096 + f * 64 + ((ch ^ (f & 7)) << 3)], &v, 16);
    }
    for (int i = tid; i < NP * 64; i += THREADS) {
        const int p = i >> 6, f = i & 63;
        b_lds[i] = (f16)((p < 7) ? bn[p * 64 + f] : bs[(p - 7) * 64 + f]);
    }
    __syncthreads();   // only barrier in the kernel

    const int lane = tid & 63;
    const int wid  = tid >> 6;
    const int l15  = lane & 15;
    const int q    = lane >> 4;
    const int gw   = blockIdx.x * (THREADS / 64) + wid;   // 0..2047

    auto wfrag = [&](int p, int ft, int kb) -> f16x8 {     // A-operand: W rows, un-swizzle
        const int f = ft * 16 + l15;
        const int chs = ((q << 1) | kb) ^ (f & 7);
        f16x8 v;
        __builtin_memcpy(&v, &w_lds[p * 4096 + f * 64 + (chs << 3)], 16);
        return v;
    };
    auto bias4 = [&](int p, int ft) -> f32x4 {             // lane's 4 biases f=ft*16+q*4+r
        f16 b[4];
        __builtin_memcpy(b, &b_lds[p * 64 + ft * 16 + q * 4], 8);
        return f32x4{(float)b[0], (float)b[1], (float)b[2], (float)b[3]};
    };

    for (int t = 0; t < TILES; ++t) {
        const long row0 = ((long)gw + (long)t * (NBLOCKS * THREADS / 64)) * 64;

        f16x8 hp[4][2], hp2[4][2];   // h_{l-1}, h_{l-2} B-frags, 64 batch rows (nb groups)

        // ---- x -> B-frags (into hp2; x is also layer-2's skip input) ----
#pragma unroll
        for (int nb = 0; nb < 4; ++nb) {
            const float* xr = x + (row0 + nb * 16 + l15) * 64;
#pragma unroll
            for (int kb = 0; kb < 2; ++kb) {
                f32x4 a, b;
                __builtin_memcpy(&a, xr + kb * 32 + q * 4, 16);
                __builtin_memcpy(&b, xr + kb * 32 + 16 + q * 4, 16);
                f16x8 v;
                v[0]=(f16)a.x; v[1]=(f16)a.y; v[2]=(f16)a.z; v[3]=(f16)a.w;
                v[4]=(f16)b.x; v[5]=(f16)b.y; v[6]=(f16)b.z; v[7]=(f16)b.w;
                hp2[nb][kb] = v;
            }
        }

        // ---- layer 1: hp = relu(x Wn0^T + bn0) ----
#pragma unroll
        for (int ft = 0; ft < 4; ++ft) {
            const f16x8 w0 = wfrag(0, ft, 0), w1 = wfrag(0, ft, 1);
            const f32x4 bv = bias4(0, ft);
#pragma unroll
            for (int nb = 0; nb < 4; ++nb) {
                f32x4 an = bv;
                an = __builtin_amdgcn_mfma_f32_16x16x32_f16(w0, hp2[nb][0], an, 0, 0, 0);
                an = __builtin_amdgcn_mfma_f32_16x16x32_f16(w1, hp2[nb][1], an, 0, 0, 0);
#pragma unroll
                for (int r = 0; r < 4; ++r)
                    hp[nb][ft >> 1][(ft & 1) * 4 + r] = (f16)fmaxf(an[r], 0.f);
            }
        }

        // ---- layers 2..6 (runtime loop: keeps lifetimes per-layer, code small) ----
#pragma unroll 1
        for (int l = 2; l <= 6; ++l) {
            const int pn = l - 1, ps = l + 5;   // 7 + (l-2)
            f16x8 hnew[4][2];
#pragma unroll
            for (int ft = 0; ft < 4; ++ft) {
                const f16x8 wn0 = wfrag(pn, ft, 0), wn1 = wfrag(pn, ft, 1);
                const f16x8 ws0 = wfrag(ps, ft, 0), ws1 = wfrag(ps, ft, 1);
                const f32x4 bnv = bias4(pn, ft),  bsv = bias4(ps, ft);
#pragma unroll
                for (int nb = 0; nb < 4; ++nb) {
                    f32x4 an = bnv, as = bsv;
                    an = __builtin_amdgcn_mfma_f32_16x16x32_f16(wn0, hp[nb][0],  an, 0, 0, 0);
                    an = __builtin_amdgcn_mfma_f32_16x16x32_f16(wn1, hp[nb][1],  an, 0, 0, 0);
                    as = __builtin_amdgcn_mfma_f32_16x16x32_f16(ws0, hp2[nb][0], as, 0, 0, 0);
                    as = __builtin_amdgcn_mfma_f32_16x16x32_f16(ws1, hp2[nb][1], as, 0, 0, 0);
#pragma unroll
                    for (int r = 0; r < 4; ++r)
                        hnew[nb][ft >> 1][(ft & 1) * 4 + r] =
                            (f16)(fmaxf(an[r], 0.f) + fmaxf(as[r], 0.f));
                }
            }
#pragma unroll
            for (int nb = 0; nb < 4; ++nb)
#pragma unroll
            for (int kb = 0; kb < 2; ++kb) {
                hp2[nb][kb] = hp[nb][kb];
                hp[nb][kb]  = hnew[nb][kb];
            }
        }

        // ---- layer 7: out = relu(h6 Wn6^T + bn6) + relu(h5 Ws5^T + bs5), fp32 store ----
#pragma unroll
        for (int ft = 0; ft < 4; ++ft) {
            const f16x8 wn0 = wfrag(6, ft, 0),  wn1 = wfrag(6, ft, 1);
            const f16x8 ws0 = wfrag(12, ft, 0), ws1 = wfrag(12, ft, 1);
            const f32x4 bnv = bias4(6, ft),     bsv = bias4(12, ft);
#pragma unroll
            for (int nb = 0; nb < 4; ++nb) {
                f32x4 an = bnv, as = bsv;
                an = __builtin_amdgcn_mfma_f32_16x16x32_f16(wn0, hp[nb][0],  an, 0, 0, 0);
                an = __builtin_amdgcn_mfma_f32_16x16x32_f16(wn1, hp[nb][1],  an, 0, 0, 0);
                as = __builtin_amdgcn_mfma_f32_16x16x32_f16(ws0, hp2[nb][0], as, 0, 0, 0);
                as = __builtin_amdgcn_mfma_f32_16x16x32_f16(ws1, hp2[nb][1], as, 0, 0, 0);
                f32x4 v;
#pragma unroll
                for (int r = 0; r < 4; ++r) v[r] = fmaxf(an[r], 0.f) + fmaxf(as[r], 0.f);
                float* orow = out + (row0 + nb * 16 + l15) * 64;
                __builtin_memcpy(orow + ft * 16 + q * 4, &v, 16);
            }
        }
    }
}

extern "C" void kernel_launch(void* const* d_in, const int* in_sizes, int n_in,
                              void* d_out, int out_size, void* d_ws, size_t ws_size,
                              hipStream_t stream) {
    (void)in_sizes; (void)n_in; (void)d_ws; (void)ws_size; (void)out_size;
    const float* x  = (const float*)d_in[0];
    const float* Wn = (const float*)d_in[1];
    const float* bn = (const float*)d_in[2];
    const float* Ws = (const float*)d_in[3];
    const float* bs = (const float*)d_in[4];
    nn_fused<<<dim3(NBLOCKS), dim3(THREADS), 0, stream>>>(x, Wn, bn, Ws, bs, (float*)d_out);
}